// Round 21
// baseline (248.476 us; speedup 1.0000x reference)
//
#include <hip/hip_runtime.h>
#include <hip/hip_bf16.h>

#define HW 4096
#define CCH 512
#define SDIM 64
#define BDIM 8

typedef __attribute__((ext_vector_type(8))) short short8;
typedef __attribute__((ext_vector_type(4))) float f32x4;

static __device__ __forceinline__ ushort f2bf(float f) {
  __hip_bfloat16 h = __float2bfloat16(f);  // RNE (cold paths only)
  return *reinterpret_cast<ushort*>(&h);
}
static __device__ __forceinline__ float bf2f(ushort u) {
  union { unsigned int u32; float f; } c;
  c.u32 = ((unsigned int)u) << 16;
  return c.f;
}
// cheap exact split: hi = truncated top-16 bits (exact subtraction), rem returned
static __device__ __forceinline__ ushort trunc_bf(float f, float* rem) {
  union { float f; unsigned int u; } a; a.f = f;
  union { float f; unsigned int u; } h; h.u = a.u & 0xFFFF0000u;
  *rem = f - h.f;                 // exact
  return (ushort)(a.u >> 16);
}
static __device__ __forceinline__ ushort rne_bf(float f) {
  union { float f; unsigned int u; } a; a.f = f;
  return (ushort)((a.u + 0x8000u) >> 16);
}
// async global->LDS DMA: each lane contributes 16B; dest = uniform base + lane*16
static __device__ __forceinline__ void gll16(const void* g, void* lds_base) {
  __builtin_amdgcn_global_load_lds(
      (const __attribute__((address_space(1))) unsigned int*)g,
      (__attribute__((address_space(3))) unsigned int*)lds_base, 16, 0, 0);
}

// K0: split Wq/Wk/Wv into bf16 hi/mid/lo triples [br][s][c]; Wl into hi/lo [c][s]
__global__ __launch_bounds__(256) void prep_kernel(const float* __restrict__ Wq,
                                                   const float* __restrict__ Wk,
                                                   const float* __restrict__ Wv,
                                                   const float* __restrict__ Wl,
                                                   ushort* __restrict__ whi,
                                                   ushort* __restrict__ wmid,
                                                   ushort* __restrict__ wlo,
                                                   ushort* __restrict__ wlhi,
                                                   ushort* __restrict__ wllo) {
  const int idx = blockIdx.x * 1024 + threadIdx.x * 4;
  if (blockIdx.y == 3) {  // Wl -> hi/lo
    float4 f = *reinterpret_cast<const float4*>(&Wl[idx]);
    ushort4 h, l;
    float r;
    h.x = trunc_bf(f.x, &r); l.x = rne_bf(r);
    h.y = trunc_bf(f.y, &r); l.y = rne_bf(r);
    h.z = trunc_bf(f.z, &r); l.z = rne_bf(r);
    h.w = trunc_bf(f.w, &r); l.w = rne_bf(r);
    *reinterpret_cast<ushort4*>(&wlhi[idx]) = h;
    *reinterpret_cast<ushort4*>(&wllo[idx]) = l;
    return;
  }
  const float* W = blockIdx.y == 0 ? Wq : (blockIdx.y == 1 ? Wk : Wv);
  float4 f = *reinterpret_cast<const float4*>(&W[idx]);
  ushort4 h, m, l;
  float r, r2;
  h.x = f2bf(f.x); r = f.x - bf2f(h.x); m.x = f2bf(r); r2 = r - bf2f(m.x); l.x = f2bf(r2);
  h.y = f2bf(f.y); r = f.y - bf2f(h.y); m.y = f2bf(r); r2 = r - bf2f(m.y); l.y = f2bf(r2);
  h.z = f2bf(f.z); r = f.z - bf2f(h.z); m.z = f2bf(r); r2 = r - bf2f(m.z); l.z = f2bf(r2);
  h.w = f2bf(f.w); r = f.w - bf2f(h.w); m.w = f2bf(r); r2 = r - bf2f(m.w); l.w = f2bf(r2);
  const size_t o = (size_t)blockIdx.y * (SDIM * CCH) + idx;
  *reinterpret_cast<ushort4*>(&whi[o])  = h;
  *reinterpret_cast<ushort4*>(&wmid[o]) = m;
  *reinterpret_cast<ushort4*>(&wlo[o])  = l;
}

// K1: 3-way-split bf16 MFMA projection (unchanged from round 17)
__global__ __launch_bounds__(256) void proj_mfma_kernel(const float* __restrict__ q,
                                                        const float* __restrict__ k,
                                                        const float* __restrict__ v,
                                                        const ushort* __restrict__ whi,
                                                        const ushort* __restrict__ wmid,
                                                        const ushort* __restrict__ wlo,
                                                        float* __restrict__ ap) {
  __shared__ float Xs[2][32 * 128];        // 32 KB
  __shared__ ushort Ws[2][3][64 * 32];     // 24 KB
  const int mt = blockIdx.x;   // hw tile of 128
  const int b = blockIdx.y;
  const int br = blockIdx.z;
  const float* x = br == 0 ? q : (br == 1 ? k : v);
  const ushort* wsrc[3] = {whi + (size_t)br * SDIM * CCH,
                           wmid + (size_t)br * SDIM * CCH,
                           wlo + (size_t)br * SDIM * CCH};
  float* apo = ap + (size_t)br * HW * 512;
  const int hw0 = mt * 128;
  const int tid = threadIdx.x;
  const int l = tid & 63;
  const int wid = tid >> 6;
  const int wstrip = wid * 32;         // wave's 32-row m-strip
  const int row16 = l & 15;
  const int kgrp = l >> 4;
  const float* xcol = x + (size_t)b * CCH * HW + hw0;
  const int rbase = 8 * wid;           // wave stages x rows [8w, 8w+8)
  const int rsub = l >> 5;             // lanes 0-31 -> +0, 32-63 -> +1
  const int wrow = wid * 16 + (l >> 2);
  const int wblk = (l & 3) ^ ((l >> 3) & 3);
  const int jp = kgrp ^ ((row16 >> 1) & 3);        // swizzled w block
  const int xswz = (kgrp & 1) << 4;                // x hw-bit-4 swizzle

  f32x4 acc_hi[2][4] = {};
  f32x4 acc_co[2][4] = {};

#define STAGE(BUF, CI)                                                            \
  do {                                                                            \
    _Pragma("unroll") for (int j = 0; j < 4; ++j) {                               \
      const int r = rbase + 2 * j + rsub;                                         \
      const int hwsrc = (((l & 31) ^ ((((r) >> 3) & 1) << 2)) * 4);               \
      gll16(xcol + (size_t)((CI) * 32 + r) * HW + hwsrc,                          \
            &Xs[BUF][(rbase + 2 * j) * 128]);                                     \
    }                                                                             \
    _Pragma("unroll") for (int lv = 0; lv < 3; ++lv)                              \
      gll16(wsrc[lv] + (size_t)wrow * CCH + (CI) * 32 + wblk * 8,                 \
            &Ws[BUF][lv][wid * 512]);                                             \
  } while (0)

  STAGE(0, 0);

  for (int ci = 0; ci < 16; ++ci) {
    __builtin_amdgcn_sched_barrier(0);
    if (ci < 15) {
      STAGE((ci + 1) & 1, ci + 1);
      __builtin_amdgcn_sched_barrier(0);
      asm volatile("s_waitcnt vmcnt(7)" ::: "memory");
    } else {
      asm volatile("s_waitcnt vmcnt(0)" ::: "memory");
    }
    __builtin_amdgcn_sched_barrier(0);
    __builtin_amdgcn_s_barrier();
    __builtin_amdgcn_sched_barrier(0);

    short8 bh[4], bm[4], bl[4];
#pragma unroll
    for (int nf = 0; nf < 4; ++nf) {
      const int woff = (nf * 16 + row16) * 32 + jp * 8;
      bh[nf] = *reinterpret_cast<const short8*>(&Ws[ci & 1][0][woff]);
      bm[nf] = *reinterpret_cast<const short8*>(&Ws[ci & 1][1][woff]);
      bl[nf] = *reinterpret_cast<const short8*>(&Ws[ci & 1][2][woff]);
    }

    const float* lw = &Xs[ci & 1][0];
#pragma unroll
    for (int mf = 0; mf < 2; ++mf) {
      const int rowA = (wstrip + mf * 16 + row16) ^ xswz;
      short8 ah, am, al;
      {
        ushort th[8], tm[8], tl[8];
#pragma unroll
        for (int i = 0; i < 8; ++i) {
          const float f = lw[(kgrp * 8 + i) * 128 + rowA];
          float r, r2;
          th[i] = trunc_bf(f, &r);
          tm[i] = trunc_bf(r, &r2);
          tl[i] = rne_bf(r2);
        }
        ah = *reinterpret_cast<const short8*>(th);
        am = *reinterpret_cast<const short8*>(tm);
        al = *reinterpret_cast<const short8*>(tl);
      }
#pragma unroll
      for (int nf = 0; nf < 4; ++nf) {
        acc_hi[mf][nf] = __builtin_amdgcn_mfma_f32_16x16x32_bf16(ah, bh[nf], acc_hi[mf][nf], 0, 0, 0);
        acc_co[mf][nf] = __builtin_amdgcn_mfma_f32_16x16x32_bf16(ah, bm[nf], acc_co[mf][nf], 0, 0, 0);
        acc_co[mf][nf] = __builtin_amdgcn_mfma_f32_16x16x32_bf16(am, bh[nf], acc_co[mf][nf], 0, 0, 0);
        acc_co[mf][nf] = __builtin_amdgcn_mfma_f32_16x16x32_bf16(am, bm[nf], acc_co[mf][nf], 0, 0, 0);
        acc_co[mf][nf] = __builtin_amdgcn_mfma_f32_16x16x32_bf16(ah, bl[nf], acc_co[mf][nf], 0, 0, 0);
        acc_co[mf][nf] = __builtin_amdgcn_mfma_f32_16x16x32_bf16(al, bh[nf], acc_co[mf][nf], 0, 0, 0);
        acc_co[mf][nf] = __builtin_amdgcn_mfma_f32_16x16x32_bf16(am, bl[nf], acc_co[mf][nf], 0, 0, 0);
        acc_co[mf][nf] = __builtin_amdgcn_mfma_f32_16x16x32_bf16(al, bm[nf], acc_co[mf][nf], 0, 0, 0);
      }
    }
    __builtin_amdgcn_sched_barrier(0);
    __builtin_amdgcn_s_barrier();
    __builtin_amdgcn_sched_barrier(0);
  }
#undef STAGE

#pragma unroll
  for (int mf = 0; mf < 2; ++mf)
#pragma unroll
    for (int nf = 0; nf < 4; ++nf)
#pragma unroll
      for (int r = 0; r < 4; ++r) {
        const int m = hw0 + wstrip + mf * 16 + kgrp * 4 + r;
        apo[(size_t)m * 512 + b * 64 + nf * 16 + row16] = acc_hi[mf][nf][r] + acc_co[mf][nf][r];
      }
}

// K2: rD[br][h][s][t] = 1 / sum_w exp( sum_b A[h,w,b,s]*B[h,w,b,t] )  (unchanged)
__global__ __launch_bounds__(512) void denom_kernel(const float* __restrict__ ap,
                                                    float* __restrict__ rD) {
  __shared__ float As[8 * 16];   // [b][s_local]
  __shared__ float Bs[8 * 64];   // [b][t]
  const int h = blockIdx.x, br = blockIdx.y, sq = blockIdx.z;
  const float* A  = ap + ((size_t)br * HW + (size_t)h * 64) * (BDIM * SDIM);
  const float* Bp = ap + ((size_t)((br + 1) % 3) * HW + (size_t)h * 64) * (BDIM * SDIM);
  const int tid = threadIdx.x;
  const int t = tid & 63;
  const int sg = tid >> 6;  // 0..7, each covers 2 s
  float D[2] = {};
  for (int w = 0; w < 64; ++w) {
    __syncthreads();
    if (tid < 128) As[tid] = A[w * 512 + (tid >> 4) * 64 + sq * 16 + (tid & 15)];
    Bs[tid] = Bp[w * 512 + tid];
    __syncthreads();
    float bv[8];
#pragma unroll
    for (int b = 0; b < 8; ++b) bv[b] = Bs[b * 64 + t];
#pragma unroll
    for (int j = 0; j < 2; ++j) {
      const int sl = sg * 2 + j;
      float m = 0.f;
#pragma unroll
      for (int b = 0; b < 8; ++b) m = fmaf(As[b * 16 + sl], bv[b], m);
      D[j] += __expf(m);
    }
  }
#pragma unroll
  for (int j = 0; j < 2; ++j)
    rD[((size_t)(br * 64 + h) * 64 + sq * 16 + sg * 2 + j) * 64 + t] = 1.0f / D[j];
}

// K3: on[br][hw][b][s] = o[s][b]/N[b], o = mtilde * C^T
//   8-WAVE version (latency-hiding): 512 threads, wave sg does 8 s-rows in
//   QK^T and one b=sg column in PV. Same fmaf chains/values -> bit-identical.
//   Staging: waves 0-5 issue one gll16 each (A/B/C halves); vmcnt(1) steady.
//   lgkmcnt(0) drains before each raw s_barrier (r20 race fix).
__global__ __launch_bounds__(512) void attn_kernel(const float* __restrict__ ap,
                                                   const float* __restrict__ rD,
                                                   float* __restrict__ on) {
  __shared__ float Tile[3][3 * 512];   // [buf][arr*512 + idx]  (A,B,C)
  __shared__ float Ms[64 * 68];        // [s][t] pad 68 (272B rows, 16B-aligned)
  const int wc = blockIdx.x, h = blockIdx.y, br = blockIdx.z;
  const float* A  = ap + ((size_t)br * HW + h * 64) * 512;
  const float* Bp = ap + ((size_t)((br + 1) % 3) * HW + h * 64) * 512;
  const float* Cp = ap + ((size_t)((br + 2) % 3) * HW + h * 64) * 512;
  const float* rDp = rD + (size_t)(br * 64 + h) * 4096;  // [s][t]
  const int tid = threadIdx.x;
  const int t = tid & 63;       // lane
  const int sg = tid >> 6;      // wave id 0..7
  const int w0 = wc * 8;

  // preload rD for this thread's 8 (s,t) cells — w-invariant
  float rdv[8];
#pragma unroll
  for (int j = 0; j < 8; ++j) rdv[j] = rDp[(sg * 8 + j) * 64 + t];

  // staging role: waves 0-5 each stage one 256-float half of one array
  const int arr = sg >> 1;             // 0=A 1=B 2=C  (sg<6)
  const int half = sg & 1;
  const float* srcw = arr == 0 ? A : (arr == 1 ? Bp : Cp);

#define STAGE_T(BUF, W)                                                   \
  do {                                                                    \
    if (sg < 6) {                                                         \
      gll16(srcw + (size_t)(W) * 512 + half * 256 + t * 4,                \
            &Tile[BUF][arr * 512 + half * 256]);                          \
    }                                                                     \
  } while (0)

  STAGE_T(0, w0);

  for (int wi = 0; wi < 8; ++wi) {
    __builtin_amdgcn_sched_barrier(0);
    if (wi < 7) {
      STAGE_T((wi + 1) % 3, w0 + wi + 1);
      __builtin_amdgcn_sched_barrier(0);
      asm volatile("s_waitcnt vmcnt(1)" ::: "memory");  // my tile-wi DMA done
    } else {
      asm volatile("s_waitcnt vmcnt(0)" ::: "memory");
    }
    __builtin_amdgcn_sched_barrier(0);
    asm volatile("s_waitcnt lgkmcnt(0)" ::: "memory");
    __builtin_amdgcn_s_barrier();        // all arrays of tile wi landed
    __builtin_amdgcn_sched_barrier(0);

    const float* Aw = &Tile[wi % 3][0];
    const float* Bw = &Tile[wi % 3][512];
    const float* Cw = &Tile[wi % 3][1024];
    {
      float bv[8];
#pragma unroll
      for (int b = 0; b < 8; ++b) bv[b] = Bw[b * 64 + t];
#pragma unroll
      for (int j4 = 0; j4 < 2; ++j4) {
        const int s0 = sg * 8 + j4 * 4;
        float4 ma = make_float4(0.f, 0.f, 0.f, 0.f);
#pragma unroll
        for (int b = 0; b < 8; ++b) {
          const float4 av = *reinterpret_cast<const float4*>(&Aw[b * 64 + s0]);
          ma.x = fmaf(av.x, bv[b], ma.x);
          ma.y = fmaf(av.y, bv[b], ma.y);
          ma.z = fmaf(av.z, bv[b], ma.z);
          ma.w = fmaf(av.w, bv[b], ma.w);
        }
        Ms[(s0 + 0) * 68 + t] = __expf(ma.x) * rdv[j4 * 4 + 0];
        Ms[(s0 + 1) * 68 + t] = __expf(ma.y) * rdv[j4 * 4 + 1];
        Ms[(s0 + 2) * 68 + t] = __expf(ma.z) * rdv[j4 * 4 + 2];
        Ms[(s0 + 3) * 68 + t] = __expf(ma.w) * rdv[j4 * 4 + 3];
      }
    }
    __builtin_amdgcn_sched_barrier(0);
    asm volatile("s_waitcnt lgkmcnt(0)" ::: "memory");  // Ms stores committed
    __builtin_amdgcn_s_barrier();        // Ms ready
    __builtin_amdgcn_sched_barrier(0);

    float o = 0.f;
#pragma unroll
    for (int tt = 0; tt < 64; tt += 4) {
      const float4 mv = *reinterpret_cast<const float4*>(&Ms[t * 68 + tt]);
      const float4 c = *reinterpret_cast<const float4*>(&Cw[sg * 64 + tt]);
      o = fmaf(mv.w, c.w, fmaf(mv.z, c.z, fmaf(mv.y, c.y, fmaf(mv.x, c.x, o))));
    }
    float n = o;
#pragma unroll
    for (int off = 32; off > 0; off >>= 1) n += __shfl_xor(n, off);
    const size_t ob = ((size_t)br * HW + h * 64 + w0 + wi) * 512;
    on[ob + (size_t)sg * 64 + t] = o * (1.0f / n);
  }
#undef STAGE_T
}

// K4: out[brb][c][hw] = sum_s on[br][hw][b][s] * wl[c][s]  (MFMA role-swap, unchanged)
__global__ __launch_bounds__(256) void out_kernel(const float* __restrict__ on,
                                                  const ushort* __restrict__ wlhi,
                                                  const ushort* __restrict__ wllo,
                                                  float* __restrict__ out) {
  __shared__ float Os[128 * 68];  // [hw_local][s] pad 68
  const int hwt = blockIdx.x;     // 32 tiles of 128 hw
  const int brb = blockIdx.y;     // 0..23
  const int br = brb >> 3, b = brb & 7;
  const int hw0 = hwt * 128;
  const int tid = threadIdx.x;
  const int l = tid & 63;
  const int wv = tid >> 6;        // wave 0..3 -> hw strip of 32
  const int l15 = l & 15;
  const int kgrp = l >> 4;

  {
    const int row = tid >> 4;
    const int s4 = (tid & 15) * 4;
#pragma unroll
    for (int it = 0; it < 8; ++it) {
      const int r = row + it * 16;
      *reinterpret_cast<float4*>(&Os[r * 68 + s4]) =
          *reinterpret_cast<const float4*>(&on[((size_t)(br * HW + hw0 + r) * 8 + b) * 64 + s4]);
    }
  }
  __syncthreads();

  short8 onh[2][2], onl[2][2];
#pragma unroll
  for (int nf = 0; nf < 2; ++nf)
#pragma unroll
    for (int ks = 0; ks < 2; ++ks) {
      const int row = wv * 32 + nf * 16 + l15;
      const float* p = &Os[row * 68 + ks * 32 + kgrp * 8];
      ushort th[8], tl[8];
#pragma unroll
      for (int i = 0; i < 8; ++i) {
        float r;
        th[i] = trunc_bf(p[i], &r);
        tl[i] = rne_bf(r);
      }
      onh[nf][ks] = *reinterpret_cast<const short8*>(th);
      onl[nf][ks] = *reinterpret_cast<const short8*>(tl);
    }

  for (int mf = 0; mf < 32; ++mf) {
    f32x4 acc[2] = {};
#pragma unroll
    for (int ks = 0; ks < 2; ++ks) {
      const size_t woff = (size_t)(mf * 16 + l15) * 64 + ks * 32 + kgrp * 8;
      const short8 wh8 = *reinterpret_cast<const short8*>(&wlhi[woff]);
      const short8 wl8 = *reinterpret_cast<const short8*>(&wllo[woff]);
#pragma unroll
      for (int nf = 0; nf < 2; ++nf) {
        acc[nf] = __builtin_amdgcn_mfma_f32_16x16x32_bf16(wh8, onh[nf][ks], acc[nf], 0, 0, 0);
        acc[nf] = __builtin_amdgcn_mfma_f32_16x16x32_bf16(wh8, onl[nf][ks], acc[nf], 0, 0, 0);
        acc[nf] = __builtin_amdgcn_mfma_f32_16x16x32_bf16(wl8, onh[nf][ks], acc[nf], 0, 0, 0);
      }
    }
#pragma unroll
    for (int nf = 0; nf < 2; ++nf)
#pragma unroll
      for (int r = 0; r < 4; ++r) {
        const int cc = mf * 16 + kgrp * 4 + r;
        out[(size_t)(brb * 512 + cc) * HW + hw0 + wv * 32 + nf * 16 + l15] = acc[nf][r];
      }
  }
}

extern "C" void kernel_launch(void* const* d_in, const int* in_sizes, int n_in,
                              void* d_out, int out_size, void* d_ws, size_t ws_size,
                              hipStream_t stream) {
  const float* q  = (const float*)d_in[0];
  const float* k  = (const float*)d_in[1];
  const float* v  = (const float*)d_in[2];
  const float* Wq = (const float*)d_in[3];
  const float* Wk = (const float*)d_in[4];
  const float* Wv = (const float*)d_in[5];
  const float* Wl = (const float*)d_in[6];
  float* out = (float*)d_out;

  float* ap = (float*)d_ws;                         // 3*HW*B*S floats = 25.2 MB
  float* rD = ap + (size_t)3 * HW * 512;            // 3*64*64*64 floats = 3.1 MB
  float* on = rD + (size_t)3 * 64 * 64 * 64;        // 3*HW*B*S floats = 25.2 MB
  ushort* whi  = (ushort*)rD;                       // 192 KB, consumed before denom overwrites rD
  ushort* wmid = whi + (size_t)3 * SDIM * CCH;
  ushort* wlo  = wmid + (size_t)3 * SDIM * CCH;
  ushort* wlhi = (ushort*)(on + (size_t)3 * HW * 512);  // 64 KB, after on
  ushort* wllo = wlhi + (size_t)SDIM * CCH;             // 64 KB

  prep_kernel<<<dim3(32, 4), 256, 0, stream>>>(Wq, Wk, Wv, Wl, whi, wmid, wlo, wlhi, wllo);
  proj_mfma_kernel<<<dim3(32, 8, 3), 256, 0, stream>>>(q, k, v, whi, wmid, wlo, ap);
  denom_kernel<<<dim3(64, 3, 4), 512, 0, stream>>>(ap, rD);
  attn_kernel<<<dim3(8, 64, 3), 512, 0, stream>>>(ap, rD, on);
  out_kernel<<<dim3(32, 24), 256, 0, stream>>>(on, wlhi, wllo, out);
}

// Round 22
// 234.696 us; speedup vs baseline: 1.0587x; 1.0587x over previous
//
#include <hip/hip_runtime.h>
#include <hip/hip_bf16.h>

#define HW 4096
#define CCH 512
#define SDIM 64
#define BDIM 8

typedef __attribute__((ext_vector_type(8))) short short8;
typedef __attribute__((ext_vector_type(4))) float f32x4;

static __device__ __forceinline__ ushort f2bf(float f) {
  __hip_bfloat16 h = __float2bfloat16(f);  // RNE (cold paths only)
  return *reinterpret_cast<ushort*>(&h);
}
static __device__ __forceinline__ float bf2f(ushort u) {
  union { unsigned int u32; float f; } c;
  c.u32 = ((unsigned int)u) << 16;
  return c.f;
}
// cheap exact split: hi = truncated top-16 bits (exact subtraction), rem returned
static __device__ __forceinline__ ushort trunc_bf(float f, float* rem) {
  union { float f; unsigned int u; } a; a.f = f;
  union { float f; unsigned int u; } h; h.u = a.u & 0xFFFF0000u;
  *rem = f - h.f;                 // exact
  return (ushort)(a.u >> 16);
}
static __device__ __forceinline__ ushort rne_bf(float f) {
  union { float f; unsigned int u; } a; a.f = f;
  return (ushort)((a.u + 0x8000u) >> 16);
}
// async global->LDS DMA: each active lane contributes 16B; dest = uniform base + lane*16
static __device__ __forceinline__ void gll16(const void* g, void* lds_base) {
  __builtin_amdgcn_global_load_lds(
      (const __attribute__((address_space(1))) unsigned int*)g,
      (__attribute__((address_space(3))) unsigned int*)lds_base, 16, 0, 0);
}

// K0: split Wq/Wk/Wv into bf16 hi/mid/lo triples [br][s][c]; Wl into hi/lo [c][s]
__global__ __launch_bounds__(256) void prep_kernel(const float* __restrict__ Wq,
                                                   const float* __restrict__ Wk,
                                                   const float* __restrict__ Wv,
                                                   const float* __restrict__ Wl,
                                                   ushort* __restrict__ whi,
                                                   ushort* __restrict__ wmid,
                                                   ushort* __restrict__ wlo,
                                                   ushort* __restrict__ wlhi,
                                                   ushort* __restrict__ wllo) {
  const int idx = blockIdx.x * 1024 + threadIdx.x * 4;
  if (blockIdx.y == 3) {  // Wl -> hi/lo
    float4 f = *reinterpret_cast<const float4*>(&Wl[idx]);
    ushort4 h, l;
    float r;
    h.x = trunc_bf(f.x, &r); l.x = rne_bf(r);
    h.y = trunc_bf(f.y, &r); l.y = rne_bf(r);
    h.z = trunc_bf(f.z, &r); l.z = rne_bf(r);
    h.w = trunc_bf(f.w, &r); l.w = rne_bf(r);
    *reinterpret_cast<ushort4*>(&wlhi[idx]) = h;
    *reinterpret_cast<ushort4*>(&wllo[idx]) = l;
    return;
  }
  const float* W = blockIdx.y == 0 ? Wq : (blockIdx.y == 1 ? Wk : Wv);
  float4 f = *reinterpret_cast<const float4*>(&W[idx]);
  ushort4 h, m, l;
  float r, r2;
  h.x = f2bf(f.x); r = f.x - bf2f(h.x); m.x = f2bf(r); r2 = r - bf2f(m.x); l.x = f2bf(r2);
  h.y = f2bf(f.y); r = f.y - bf2f(h.y); m.y = f2bf(r); r2 = r - bf2f(m.y); l.y = f2bf(r2);
  h.z = f2bf(f.z); r = f.z - bf2f(h.z); m.z = f2bf(r); r2 = r - bf2f(m.z); l.z = f2bf(r2);
  h.w = f2bf(f.w); r = f.w - bf2f(h.w); m.w = f2bf(r); r2 = r - bf2f(m.w); l.w = f2bf(r2);
  const size_t o = (size_t)blockIdx.y * (SDIM * CCH) + idx;
  *reinterpret_cast<ushort4*>(&whi[o])  = h;
  *reinterpret_cast<ushort4*>(&wmid[o]) = m;
  *reinterpret_cast<ushort4*>(&wlo[o])  = l;
}

// K1: 3-way-split bf16 MFMA projection (unchanged from round 17)
__global__ __launch_bounds__(256) void proj_mfma_kernel(const float* __restrict__ q,
                                                        const float* __restrict__ k,
                                                        const float* __restrict__ v,
                                                        const ushort* __restrict__ whi,
                                                        const ushort* __restrict__ wmid,
                                                        const ushort* __restrict__ wlo,
                                                        float* __restrict__ ap) {
  __shared__ float Xs[2][32 * 128];        // 32 KB
  __shared__ ushort Ws[2][3][64 * 32];     // 24 KB
  const int mt = blockIdx.x;   // hw tile of 128
  const int b = blockIdx.y;
  const int br = blockIdx.z;
  const float* x = br == 0 ? q : (br == 1 ? k : v);
  const ushort* wsrc[3] = {whi + (size_t)br * SDIM * CCH,
                           wmid + (size_t)br * SDIM * CCH,
                           wlo + (size_t)br * SDIM * CCH};
  float* apo = ap + (size_t)br * HW * 512;
  const int hw0 = mt * 128;
  const int tid = threadIdx.x;
  const int l = tid & 63;
  const int wid = tid >> 6;
  const int wstrip = wid * 32;         // wave's 32-row m-strip
  const int row16 = l & 15;
  const int kgrp = l >> 4;
  const float* xcol = x + (size_t)b * CCH * HW + hw0;
  const int rbase = 8 * wid;           // wave stages x rows [8w, 8w+8)
  const int rsub = l >> 5;             // lanes 0-31 -> +0, 32-63 -> +1
  const int wrow = wid * 16 + (l >> 2);
  const int wblk = (l & 3) ^ ((l >> 3) & 3);
  const int jp = kgrp ^ ((row16 >> 1) & 3);        // swizzled w block
  const int xswz = (kgrp & 1) << 4;                // x hw-bit-4 swizzle

  f32x4 acc_hi[2][4] = {};
  f32x4 acc_co[2][4] = {};

#define STAGE(BUF, CI)                                                            \
  do {                                                                            \
    _Pragma("unroll") for (int j = 0; j < 4; ++j) {                               \
      const int r = rbase + 2 * j + rsub;                                         \
      const int hwsrc = (((l & 31) ^ ((((r) >> 3) & 1) << 2)) * 4);               \
      gll16(xcol + (size_t)((CI) * 32 + r) * HW + hwsrc,                          \
            &Xs[BUF][(rbase + 2 * j) * 128]);                                     \
    }                                                                             \
    _Pragma("unroll") for (int lv = 0; lv < 3; ++lv)                              \
      gll16(wsrc[lv] + (size_t)wrow * CCH + (CI) * 32 + wblk * 8,                 \
            &Ws[BUF][lv][wid * 512]);                                             \
  } while (0)

  STAGE(0, 0);

  for (int ci = 0; ci < 16; ++ci) {
    __builtin_amdgcn_sched_barrier(0);
    if (ci < 15) {
      STAGE((ci + 1) & 1, ci + 1);
      __builtin_amdgcn_sched_barrier(0);
      asm volatile("s_waitcnt vmcnt(7)" ::: "memory");
    } else {
      asm volatile("s_waitcnt vmcnt(0)" ::: "memory");
    }
    __builtin_amdgcn_sched_barrier(0);
    __builtin_amdgcn_s_barrier();
    __builtin_amdgcn_sched_barrier(0);

    short8 bh[4], bm[4], bl[4];
#pragma unroll
    for (int nf = 0; nf < 4; ++nf) {
      const int woff = (nf * 16 + row16) * 32 + jp * 8;
      bh[nf] = *reinterpret_cast<const short8*>(&Ws[ci & 1][0][woff]);
      bm[nf] = *reinterpret_cast<const short8*>(&Ws[ci & 1][1][woff]);
      bl[nf] = *reinterpret_cast<const short8*>(&Ws[ci & 1][2][woff]);
    }

    const float* lw = &Xs[ci & 1][0];
#pragma unroll
    for (int mf = 0; mf < 2; ++mf) {
      const int rowA = (wstrip + mf * 16 + row16) ^ xswz;
      short8 ah, am, al;
      {
        ushort th[8], tm[8], tl[8];
#pragma unroll
        for (int i = 0; i < 8; ++i) {
          const float f = lw[(kgrp * 8 + i) * 128 + rowA];
          float r, r2;
          th[i] = trunc_bf(f, &r);
          tm[i] = trunc_bf(r, &r2);
          tl[i] = rne_bf(r2);
        }
        ah = *reinterpret_cast<const short8*>(th);
        am = *reinterpret_cast<const short8*>(tm);
        al = *reinterpret_cast<const short8*>(tl);
      }
#pragma unroll
      for (int nf = 0; nf < 4; ++nf) {
        acc_hi[mf][nf] = __builtin_amdgcn_mfma_f32_16x16x32_bf16(ah, bh[nf], acc_hi[mf][nf], 0, 0, 0);
        acc_co[mf][nf] = __builtin_amdgcn_mfma_f32_16x16x32_bf16(ah, bm[nf], acc_co[mf][nf], 0, 0, 0);
        acc_co[mf][nf] = __builtin_amdgcn_mfma_f32_16x16x32_bf16(am, bh[nf], acc_co[mf][nf], 0, 0, 0);
        acc_co[mf][nf] = __builtin_amdgcn_mfma_f32_16x16x32_bf16(am, bm[nf], acc_co[mf][nf], 0, 0, 0);
        acc_co[mf][nf] = __builtin_amdgcn_mfma_f32_16x16x32_bf16(ah, bl[nf], acc_co[mf][nf], 0, 0, 0);
        acc_co[mf][nf] = __builtin_amdgcn_mfma_f32_16x16x32_bf16(al, bh[nf], acc_co[mf][nf], 0, 0, 0);
        acc_co[mf][nf] = __builtin_amdgcn_mfma_f32_16x16x32_bf16(am, bl[nf], acc_co[mf][nf], 0, 0, 0);
        acc_co[mf][nf] = __builtin_amdgcn_mfma_f32_16x16x32_bf16(al, bm[nf], acc_co[mf][nf], 0, 0, 0);
      }
    }
    __builtin_amdgcn_sched_barrier(0);
    __builtin_amdgcn_s_barrier();
    __builtin_amdgcn_sched_barrier(0);
  }
#undef STAGE

#pragma unroll
  for (int mf = 0; mf < 2; ++mf)
#pragma unroll
    for (int nf = 0; nf < 4; ++nf)
#pragma unroll
      for (int r = 0; r < 4; ++r) {
        const int m = hw0 + wstrip + mf * 16 + kgrp * 4 + r;
        apo[(size_t)m * 512 + b * 64 + nf * 16 + row16] = acc_hi[mf][nf][r] + acc_co[mf][nf][r];
      }
}

// K2: rD[br][h][s][t] = 1 / sum_w exp( sum_b A[h,w,b,s]*B[h,w,b,t] )
//   DMA-pipelined: ring-3 LDS, waves 0-2 stage As/Bs via gll16 (per-lane
//   source addrs handle As's strided rows; 32-lane exec-masked DMA for the
//   512B As slice), vmcnt(1) steady, ONE raw barrier per w (ring-3 safety:
//   barrier(w-1) => all waves finished compute(w-2), the buffer DMA(w+1)
//   overwrites). No ds_writes -> no lgkm drain needed. Bit-identical rD.
__global__ __launch_bounds__(512) void denom_kernel(const float* __restrict__ ap,
                                                    float* __restrict__ rD) {
  __shared__ float As[3][128];   // [buf][b*16 + s_local]
  __shared__ float Bs[3][512];   // [buf][b*64 + t]
  const int h = blockIdx.x, br = blockIdx.y, sq = blockIdx.z;
  const float* A  = ap + ((size_t)br * HW + (size_t)h * 64) * 512;
  const float* Bp = ap + ((size_t)((br + 1) % 3) * HW + (size_t)h * 64) * 512;
  const int tid = threadIdx.x;
  const int t = tid & 63;
  const int sg = tid >> 6;  // wave 0..7
  float D[2] = {};

#define STAGE_D(BUF, W)                                                        \
  do {                                                                         \
    if (sg == 0) {                                                             \
      if (t < 32)                                                              \
        gll16(A + (size_t)(W) * 512 + (t >> 2) * 64 + sq * 16 + (t & 3) * 4,   \
              &As[BUF][0]);                                                    \
    } else if (sg == 1) {                                                      \
      gll16(Bp + (size_t)(W) * 512 + t * 4, &Bs[BUF][0]);                      \
    } else if (sg == 2) {                                                      \
      gll16(Bp + (size_t)(W) * 512 + 256 + t * 4, &Bs[BUF][256]);              \
    }                                                                          \
  } while (0)

  STAGE_D(0, 0);

  for (int w = 0; w < 64; ++w) {
    __builtin_amdgcn_sched_barrier(0);
    if (w < 63) {
      STAGE_D((w + 1) % 3, w + 1);
      __builtin_amdgcn_sched_barrier(0);
      asm volatile("s_waitcnt vmcnt(1)" ::: "memory");  // my w-tile DMA done; w+1 in flight
    } else {
      asm volatile("s_waitcnt vmcnt(0)" ::: "memory");
    }
    __builtin_amdgcn_sched_barrier(0);
    __builtin_amdgcn_s_barrier();        // tile w landed (all staging waves)
    __builtin_amdgcn_sched_barrier(0);

    const float* Aw = &As[w % 3][0];
    const float* Bw = &Bs[w % 3][0];
    float bv[8];
#pragma unroll
    for (int b = 0; b < 8; ++b) bv[b] = Bw[b * 64 + t];
#pragma unroll
    for (int j = 0; j < 2; ++j) {
      const int sl = sg * 2 + j;
      float m = 0.f;
#pragma unroll
      for (int b = 0; b < 8; ++b) m = fmaf(Aw[b * 16 + sl], bv[b], m);
      D[j] += __expf(m);
    }
  }
#undef STAGE_D

#pragma unroll
  for (int j = 0; j < 2; ++j)
    rD[((size_t)(br * 64 + h) * 64 + sq * 16 + sg * 2 + j) * 64 + t] = 1.0f / D[j];
}

// K3: on[br][hw][b][s] = o[s][b]/N[b], o = mtilde * C^T
//   r20 4-wave version (best known): rD in regs, ring-3 DMA staging,
//   vectorized LDS, lgkmcnt(0) drains before raw barriers.
__global__ __launch_bounds__(256) void attn_kernel(const float* __restrict__ ap,
                                                   const float* __restrict__ rD,
                                                   float* __restrict__ on) {
  __shared__ float Tile[3][3 * 512];   // [buf][arr*512 + idx]  (A,B,C)
  __shared__ float Ms[64 * 68];        // [s][t] pad 68 (272B rows, 16B-aligned)
  const int wc = blockIdx.x, h = blockIdx.y, br = blockIdx.z;
  const float* A  = ap + ((size_t)br * HW + h * 64) * 512;
  const float* Bp = ap + ((size_t)((br + 1) % 3) * HW + h * 64) * 512;
  const float* Cp = ap + ((size_t)((br + 2) % 3) * HW + h * 64) * 512;
  const float* rDp = rD + (size_t)(br * 64 + h) * 4096;  // [s][t]
  const int tid = threadIdx.x;
  const int t = tid & 63;       // lane
  const int sg = tid >> 6;      // wave id 0..3
  const int w0 = wc * 8;

  // preload rD for this thread's 16 (s,t) cells — w-invariant
  float rdv[16];
#pragma unroll
  for (int j = 0; j < 16; ++j) rdv[j] = rDp[(sg * 16 + j) * 64 + t];

  const float* src = sg == 0 ? A : (sg == 1 ? Bp : Cp);

#define STAGE_T(BUF, W)                                                   \
  do {                                                                    \
    if (sg < 3) {                                                         \
      _Pragma("unroll") for (int j = 0; j < 2; ++j)                       \
        gll16(src + (size_t)(W) * 512 + j * 256 + t * 4,                  \
              &Tile[BUF][sg * 512 + j * 256]);                            \
    }                                                                     \
  } while (0)

  STAGE_T(0, w0);

  for (int wi = 0; wi < 8; ++wi) {
    __builtin_amdgcn_sched_barrier(0);
    if (wi < 7) {
      STAGE_T((wi + 1) % 3, w0 + wi + 1);
      __builtin_amdgcn_sched_barrier(0);
      asm volatile("s_waitcnt vmcnt(2)" ::: "memory");  // my tile-wi DMAs done
    } else {
      asm volatile("s_waitcnt vmcnt(0)" ::: "memory");
    }
    __builtin_amdgcn_sched_barrier(0);
    asm volatile("s_waitcnt lgkmcnt(0)" ::: "memory");  // drain my LDS ops pre-barrier
    __builtin_amdgcn_s_barrier();        // all arrays of tile wi landed
    __builtin_amdgcn_sched_barrier(0);

    const float* Aw = &Tile[wi % 3][0];
    const float* Bw = &Tile[wi % 3][512];
    const float* Cw = &Tile[wi % 3][1024];
    {
      float bv[8];
#pragma unroll
      for (int b = 0; b < 8; ++b) bv[b] = Bw[b * 64 + t];
#pragma unroll
      for (int j4 = 0; j4 < 4; ++j4) {
        const int s0 = sg * 16 + j4 * 4;
        float4 ma = make_float4(0.f, 0.f, 0.f, 0.f);
#pragma unroll
        for (int b = 0; b < 8; ++b) {
          const float4 av = *reinterpret_cast<const float4*>(&Aw[b * 64 + s0]);
          ma.x = fmaf(av.x, bv[b], ma.x);
          ma.y = fmaf(av.y, bv[b], ma.y);
          ma.z = fmaf(av.z, bv[b], ma.z);
          ma.w = fmaf(av.w, bv[b], ma.w);
        }
        Ms[(s0 + 0) * 68 + t] = __expf(ma.x) * rdv[j4 * 4 + 0];
        Ms[(s0 + 1) * 68 + t] = __expf(ma.y) * rdv[j4 * 4 + 1];
        Ms[(s0 + 2) * 68 + t] = __expf(ma.z) * rdv[j4 * 4 + 2];
        Ms[(s0 + 3) * 68 + t] = __expf(ma.w) * rdv[j4 * 4 + 3];
      }
    }
    __builtin_amdgcn_sched_barrier(0);
    asm volatile("s_waitcnt lgkmcnt(0)" ::: "memory");  // Ms stores committed
    __builtin_amdgcn_s_barrier();        // Ms ready
    __builtin_amdgcn_sched_barrier(0);

    float o0 = 0.f, o1 = 0.f;
#pragma unroll
    for (int tt = 0; tt < 64; tt += 4) {
      const float4 mv = *reinterpret_cast<const float4*>(&Ms[t * 68 + tt]);
      const float4 c0 = *reinterpret_cast<const float4*>(&Cw[sg * 64 + tt]);
      const float4 c1 = *reinterpret_cast<const float4*>(&Cw[(sg + 4) * 64 + tt]);
      o0 = fmaf(mv.w, c0.w, fmaf(mv.z, c0.z, fmaf(mv.y, c0.y, fmaf(mv.x, c0.x, o0))));
      o1 = fmaf(mv.w, c1.w, fmaf(mv.z, c1.z, fmaf(mv.y, c1.y, fmaf(mv.x, c1.x, o1))));
    }
    float n0 = o0, n1 = o1;
#pragma unroll
    for (int off = 32; off > 0; off >>= 1) {
      n0 += __shfl_xor(n0, off);
      n1 += __shfl_xor(n1, off);
    }
    const float r0 = 1.0f / n0, r1 = 1.0f / n1;
    const size_t ob = ((size_t)br * HW + h * 64 + w0 + wi) * 512;
    on[ob + (size_t)sg * 64 + t] = o0 * r0;
    on[ob + (size_t)(sg + 4) * 64 + t] = o1 * r1;
  }
#undef STAGE_T
}

// K4: out[brb][c][hw] = sum_s on[br][hw][b][s] * wl[c][s]  (MFMA role-swap, unchanged)
__global__ __launch_bounds__(256) void out_kernel(const float* __restrict__ on,
                                                  const ushort* __restrict__ wlhi,
                                                  const ushort* __restrict__ wllo,
                                                  float* __restrict__ out) {
  __shared__ float Os[128 * 68];  // [hw_local][s] pad 68
  const int hwt = blockIdx.x;     // 32 tiles of 128 hw
  const int brb = blockIdx.y;     // 0..23
  const int br = brb >> 3, b = brb & 7;
  const int hw0 = hwt * 128;
  const int tid = threadIdx.x;
  const int l = tid & 63;
  const int wv = tid >> 6;        // wave 0..3 -> hw strip of 32
  const int l15 = l & 15;
  const int kgrp = l >> 4;

  {
    const int row = tid >> 4;
    const int s4 = (tid & 15) * 4;
#pragma unroll
    for (int it = 0; it < 8; ++it) {
      const int r = row + it * 16;
      *reinterpret_cast<float4*>(&Os[r * 68 + s4]) =
          *reinterpret_cast<const float4*>(&on[((size_t)(br * HW + hw0 + r) * 8 + b) * 64 + s4]);
    }
  }
  __syncthreads();

  short8 onh[2][2], onl[2][2];
#pragma unroll
  for (int nf = 0; nf < 2; ++nf)
#pragma unroll
    for (int ks = 0; ks < 2; ++ks) {
      const int row = wv * 32 + nf * 16 + l15;
      const float* p = &Os[row * 68 + ks * 32 + kgrp * 8];
      ushort th[8], tl[8];
#pragma unroll
      for (int i = 0; i < 8; ++i) {
        float r;
        th[i] = trunc_bf(p[i], &r);
        tl[i] = rne_bf(r);
      }
      onh[nf][ks] = *reinterpret_cast<const short8*>(th);
      onl[nf][ks] = *reinterpret_cast<const short8*>(tl);
    }

  for (int mf = 0; mf < 32; ++mf) {
    f32x4 acc[2] = {};
#pragma unroll
    for (int ks = 0; ks < 2; ++ks) {
      const size_t woff = (size_t)(mf * 16 + l15) * 64 + ks * 32 + kgrp * 8;
      const short8 wh8 = *reinterpret_cast<const short8*>(&wlhi[woff]);
      const short8 wl8 = *reinterpret_cast<const short8*>(&wllo[woff]);
#pragma unroll
      for (int nf = 0; nf < 2; ++nf) {
        acc[nf] = __builtin_amdgcn_mfma_f32_16x16x32_bf16(wh8, onh[nf][ks], acc[nf], 0, 0, 0);
        acc[nf] = __builtin_amdgcn_mfma_f32_16x16x32_bf16(wh8, onl[nf][ks], acc[nf], 0, 0, 0);
        acc[nf] = __builtin_amdgcn_mfma_f32_16x16x32_bf16(wl8, onh[nf][ks], acc[nf], 0, 0, 0);
      }
    }
#pragma unroll
    for (int nf = 0; nf < 2; ++nf)
#pragma unroll
      for (int r = 0; r < 4; ++r) {
        const int cc = mf * 16 + kgrp * 4 + r;
        out[(size_t)(brb * 512 + cc) * HW + hw0 + wv * 32 + nf * 16 + l15] = acc[nf][r];
      }
  }
}

extern "C" void kernel_launch(void* const* d_in, const int* in_sizes, int n_in,
                              void* d_out, int out_size, void* d_ws, size_t ws_size,
                              hipStream_t stream) {
  const float* q  = (const float*)d_in[0];
  const float* k  = (const float*)d_in[1];
  const float* v  = (const float*)d_in[2];
  const float* Wq = (const float*)d_in[3];
  const float* Wk = (const float*)d_in[4];
  const float* Wv = (const float*)d_in[5];
  const float* Wl = (const float*)d_in[6];
  float* out = (float*)d_out;

  float* ap = (float*)d_ws;                         // 3*HW*B*S floats = 25.2 MB
  float* rD = ap + (size_t)3 * HW * 512;            // 3*64*64*64 floats = 3.1 MB
  float* on = rD + (size_t)3 * 64 * 64 * 64;        // 3*HW*B*S floats = 25.2 MB
  ushort* whi  = (ushort*)rD;                       // 192 KB, consumed before denom overwrites rD
  ushort* wmid = whi + (size_t)3 * SDIM * CCH;
  ushort* wlo  = wmid + (size_t)3 * SDIM * CCH;
  ushort* wlhi = (ushort*)(on + (size_t)3 * HW * 512);  // 64 KB, after on
  ushort* wllo = wlhi + (size_t)SDIM * CCH;             // 64 KB

  prep_kernel<<<dim3(32, 4), 256, 0, stream>>>(Wq, Wk, Wv, Wl, whi, wmid, wlo, wlhi, wllo);
  proj_mfma_kernel<<<dim3(32, 8, 3), 256, 0, stream>>>(q, k, v, whi, wmid, wlo, ap);
  denom_kernel<<<dim3(64, 3, 4), 512, 0, stream>>>(ap, rD);
  attn_kernel<<<dim3(8, 64, 3), 256, 0, stream>>>(ap, rD, on);
  out_kernel<<<dim3(32, 24), 256, 0, stream>>>(on, wlhi, wllo, out);
}